// Round 1
// baseline (292.492 us; speedup 1.0000x reference)
//
#include <hip/hip_runtime.h>
#include <cstdint>
#include <cstddef>

// ---------- types ----------
typedef __attribute__((ext_vector_type(8))) short  bf16x8;   // 8 bf16 = 4 VGPR (MFMA A/B frag)
typedef __attribute__((ext_vector_type(4))) float  f32x4;    // MFMA C/D frag
typedef __attribute__((ext_vector_type(4))) unsigned short u16x4;

#define LOG2E 1.44269504088896340736f

// fp32 -> bf16 round-to-nearest-even (finite inputs)
__device__ __forceinline__ unsigned short f2bf(float f) {
  unsigned int u = __builtin_bit_cast(unsigned int, f);
  u += 0x7fffu + ((u >> 16) & 1u);
  return (unsigned short)(u >> 16);
}
__device__ __forceinline__ float bf2f(unsigned short s) {
  unsigned int u = ((unsigned int)s) << 16;
  return __builtin_bit_cast(float, u);
}

// async global->LDS, 16B per lane. LDS dest is wave-uniform base + lane*16;
// callers arrange lane's lds ptr = base + lane*16 matching lane's gptr.
__device__ __forceinline__ void gll16(const void* g, void* l) {
  __builtin_amdgcn_global_load_lds(
      (const __attribute__((address_space(1))) unsigned int*)g,
      (__attribute__((address_space(3))) unsigned int*)l, 16, 0, 0);
}

// ---------- elementwise fp32 -> bf16 ----------
__global__ void cvt_f32_bf16(const float* __restrict__ in, unsigned short* __restrict__ out, int n4) {
  int i = blockIdx.x * blockDim.x + threadIdx.x;
  if (i < n4) {
    float4 v = ((const float4*)in)[i];
    u16x4 o;
    o[0] = f2bf(v.x); o[1] = f2bf(v.y); o[2] = f2bf(v.z); o[3] = f2bf(v.w);
    ((u16x4*)out)[i] = o;
  }
}

// ---------- transpose fp32(rows x cols) -> bf16(cols x rows) ----------
__global__ void tr_f32_bf16(const float* __restrict__ in, unsigned short* __restrict__ out,
                            int rows, int cols) {
  __shared__ unsigned short s[64][68];
  int t = threadIdx.x;
  int r0 = blockIdx.y * 64, c0 = blockIdx.x * 64;
  int tr = t >> 4, tc4 = (t & 15) * 4;
  for (int i = 0; i < 4; ++i) {
    int r = tr + i * 16;
    float4 v = *(const float4*)(in + (size_t)(r0 + r) * cols + c0 + tc4);
    s[r][tc4 + 0] = f2bf(v.x); s[r][tc4 + 1] = f2bf(v.y);
    s[r][tc4 + 2] = f2bf(v.z); s[r][tc4 + 3] = f2bf(v.w);
  }
  __syncthreads();
  for (int i = 0; i < 4; ++i) {
    int oc = tr + i * 16;   // output row  == input col c0+oc
    int orr = tc4;          // output col base == input row r0+tc4
    u16x4 o;
    o[0] = s[orr + 0][oc]; o[1] = s[orr + 1][oc];
    o[2] = s[orr + 2][oc]; o[3] = s[orr + 3][oc];
    *(u16x4*)(out + (size_t)(c0 + oc) * rows + r0 + orr) = o;
  }
}

// ---------- transpose bf16(rows x cols) -> bf16(cols x rows) ----------
__global__ void tr_bf16(const unsigned short* __restrict__ in, unsigned short* __restrict__ out,
                        int rows, int cols) {
  __shared__ unsigned short s[64][68];
  int t = threadIdx.x;
  int r0 = blockIdx.y * 64, c0 = blockIdx.x * 64;
  int tr = t >> 4, tc4 = (t & 15) * 4;
  for (int i = 0; i < 4; ++i) {
    int r = tr + i * 16;
    u16x4 v = *(const u16x4*)(in + (size_t)(r0 + r) * cols + c0 + tc4);
    s[r][tc4 + 0] = v[0]; s[r][tc4 + 1] = v[1]; s[r][tc4 + 2] = v[2]; s[r][tc4 + 3] = v[3];
  }
  __syncthreads();
  for (int i = 0; i < 4; ++i) {
    int oc = tr + i * 16;
    int orr = tc4;
    u16x4 o;
    o[0] = s[orr + 0][oc]; o[1] = s[orr + 1][oc];
    o[2] = s[orr + 2][oc]; o[3] = s[orr + 3][oc];
    *(u16x4*)(out + (size_t)(c0 + oc) * rows + r0 + orr) = o;
  }
}

// ---------- NT GEMM: C[M][N] = A[M][K] * B[N][K]^T, bf16 in, bf16/f32 out ----------
// 128x128 tile, BK=32, 256 thr = 4 waves (2x2), each wave 64x64 = 4x4 MFMA 16x16x32.
// Batched over blockIdx.z selecting (B, C) pair. m97-style global_load_lds staging.
template <bool BF16OUT>
__global__ __launch_bounds__(256) void gemm_nt(
    const unsigned short* __restrict__ A,
    const unsigned short* __restrict__ B0, const unsigned short* __restrict__ B1,
    const unsigned short* __restrict__ B2,
    void* __restrict__ C0, void* __restrict__ C1, void* __restrict__ C2,
    int M, int N, int K) {
  const unsigned short* B = blockIdx.z == 0 ? B0 : (blockIdx.z == 1 ? B1 : B2);
  void* Cv = blockIdx.z == 0 ? C0 : (blockIdx.z == 1 ? C1 : C2);

  __shared__ unsigned short As[128 * 32];
  __shared__ unsigned short Bs[128 * 32];

  int tid = threadIdx.x, w = tid >> 6, lane = tid & 63;
  int lo = lane & 15, quad = lane >> 4;
  int m0 = blockIdx.y * 128, n0 = blockIdx.x * 128;
  int wm = (w >> 1) * 64, wn = (w & 1) * 64;

  f32x4 zero4 = {0.f, 0.f, 0.f, 0.f};
  f32x4 acc[4][4];
  for (int mi = 0; mi < 4; ++mi)
    for (int ni = 0; ni < 4; ++ni) acc[mi][ni] = zero4;

  // staging map: chunk c in [0,8): lds elem = c*512 + lane*8; row = c*16 + lane/4; kk = (lane&3)*8
  int c0 = w * 2;
  int rA0 = c0 * 16 + (lane >> 2);
  int kk = (lane & 3) * 8;
  int ldsOfs = c0 * 512 + lane * 8;
  const unsigned short* Ag = A + (size_t)(m0 + rA0) * K + kk;
  const unsigned short* Bg = B + (size_t)(n0 + rA0) * K + kk;

  for (int k0 = 0; k0 < K; k0 += 32) {
    gll16(Ag + k0, As + ldsOfs);
    gll16(Ag + (size_t)16 * K + k0, As + ldsOfs + 512);
    gll16(Bg + k0, Bs + ldsOfs);
    gll16(Bg + (size_t)16 * K + k0, Bs + ldsOfs + 512);
    __syncthreads();

    bf16x8 af[4], bfr[4];
    for (int mi = 0; mi < 4; ++mi)
      af[mi] = *(const bf16x8*)(As + (wm + mi * 16 + lo) * 32 + quad * 8);
    for (int ni = 0; ni < 4; ++ni)
      bfr[ni] = *(const bf16x8*)(Bs + (wn + ni * 16 + lo) * 32 + quad * 8);
    for (int mi = 0; mi < 4; ++mi)
      for (int ni = 0; ni < 4; ++ni)
        acc[mi][ni] = __builtin_amdgcn_mfma_f32_16x16x32_bf16(af[mi], bfr[ni], acc[mi][ni], 0, 0, 0);
    __syncthreads();
  }

  for (int mi = 0; mi < 4; ++mi)
    for (int ni = 0; ni < 4; ++ni)
      for (int i = 0; i < 4; ++i) {
        int r = m0 + wm + mi * 16 + quad * 4 + i;
        int c = n0 + wn + ni * 16 + lo;
        if (BF16OUT)
          ((unsigned short*)Cv)[(size_t)r * N + c] = f2bf(acc[mi][ni][i]);
        else
          ((float*)Cv)[(size_t)r * N + c] = acc[mi][ni][i];
      }
}

// ---------- flash attention (no-max online softmax) ----------
// Q,K: bf16 [4096][1024] (row = b*2048+l, col = h*64+d). Q pre-scaled in LDS by ent[h]/8*log2e.
// Vt: bf16 [1024][4096] (row = h*64+d, col = b*2048+l).
// O:  bf16 [4096][1024].
// Block: one (b,h) x 64 q-rows; 4 waves, 16 q-rows/wave; KV tiles of 64.
__global__ __launch_bounds__(256) void flash_attn(
    const unsigned short* __restrict__ Q, const unsigned short* __restrict__ K,
    const unsigned short* __restrict__ Vt, const float* __restrict__ ent,
    unsigned short* __restrict__ O) {
  int tid = threadIdx.x, w = tid >> 6, lane = tid & 63;
  int lo = lane & 15, quad = lane >> 4;
  int b = blockIdx.y >> 4, h = blockIdx.y & 15;
  int q0 = blockIdx.x * 64;
  float scale = ent[h] * (0.125f * LOG2E);

  __shared__ unsigned short Qs[64 * 64];
  __shared__ unsigned short Ks[64 * 64];
  __shared__ unsigned short Vts[64 * 64];   // [d][l]
  __shared__ unsigned short Ps[4][16 * 64]; // per-wave P tile [q][l]

  // stage Q, folding scale (and log2e) into it
  for (int it = 0; it < 2; ++it) {
    int e = (it * 256 + tid) * 8;
    int r = e >> 6, d = e & 63;
    uint4 v = *(const uint4*)(Q + (size_t)(b * 2048 + q0 + r) * 1024 + h * 64 + d);
    unsigned int* pv = (unsigned int*)&v;
    uint4 o;
    unsigned int* po = (unsigned int*)&o;
    for (int j = 0; j < 4; ++j) {
      float f0 = bf2f((unsigned short)(pv[j] & 0xffffu)) * scale;
      float f1 = bf2f((unsigned short)(pv[j] >> 16)) * scale;
      po[j] = (unsigned int)f2bf(f0) | ((unsigned int)f2bf(f1) << 16);
    }
    *(uint4*)(Qs + e) = o;
  }
  __syncthreads();

  bf16x8 aq0 = *(const bf16x8*)(Qs + (w * 16 + lo) * 64 + quad * 8);
  bf16x8 aq1 = *(const bf16x8*)(Qs + (w * 16 + lo) * 64 + 32 + quad * 8);

  f32x4 zero4 = {0.f, 0.f, 0.f, 0.f};
  f32x4 acco[4];
  for (int di = 0; di < 4; ++di) acco[di] = zero4;
  float lsum[4] = {0.f, 0.f, 0.f, 0.f};

  int c0 = w * 2;
  unsigned short* Pw = Ps[w];

  for (int kv0 = 0; kv0 < 2048; kv0 += 64) {
    // stage K tile [l][d] and Vt tile [d][l] via async direct-to-LDS
    for (int j = 0; j < 2; ++j) {
      int c = c0 + j;
      int r = c * 8 + (lane >> 3);
      int d = (lane & 7) * 8;
      gll16(K + (size_t)(b * 2048 + kv0 + r) * 1024 + h * 64 + d, Ks + c * 512 + lane * 8);
      gll16(Vt + (size_t)(h * 64 + r) * 4096 + b * 2048 + kv0 + d, Vts + c * 512 + lane * 8);
    }
    __syncthreads();

    // S = Qs . Ks^T  (16 q x 64 kv per wave)
    f32x4 accs[4];
    for (int ni = 0; ni < 4; ++ni) accs[ni] = zero4;
    for (int ni = 0; ni < 4; ++ni) {
      bf16x8 bk0 = *(const bf16x8*)(Ks + (ni * 16 + lo) * 64 + quad * 8);
      bf16x8 bk1 = *(const bf16x8*)(Ks + (ni * 16 + lo) * 64 + 32 + quad * 8);
      accs[ni] = __builtin_amdgcn_mfma_f32_16x16x32_bf16(aq0, bk0, accs[ni], 0, 0, 0);
      accs[ni] = __builtin_amdgcn_mfma_f32_16x16x32_bf16(aq1, bk1, accs[ni], 0, 0, 0);
    }
    // P = 2^S (scale already folded); accumulate row sums; C-layout -> A-layout via LDS
    for (int ni = 0; ni < 4; ++ni)
      for (int i = 0; i < 4; ++i) {
        float p = exp2f(accs[ni][i]);
        lsum[i] += p;
        Pw[(quad * 4 + i) * 64 + ni * 16 + lo] = f2bf(p);
      }
    // O += P . V  (same-wave LDS RAW: in-order per wave / compiler-waited)
    bf16x8 ap0 = *(const bf16x8*)(Pw + lo * 64 + quad * 8);
    bf16x8 ap1 = *(const bf16x8*)(Pw + lo * 64 + 32 + quad * 8);
    for (int di = 0; di < 4; ++di) {
      bf16x8 bv0 = *(const bf16x8*)(Vts + (di * 16 + lo) * 64 + quad * 8);
      bf16x8 bv1 = *(const bf16x8*)(Vts + (di * 16 + lo) * 64 + 32 + quad * 8);
      acco[di] = __builtin_amdgcn_mfma_f32_16x16x32_bf16(ap0, bv0, acco[di], 0, 0, 0);
      acco[di] = __builtin_amdgcn_mfma_f32_16x16x32_bf16(ap1, bv1, acco[di], 0, 0, 0);
    }
    __syncthreads();
  }

  // reduce row sums across the 16 lanes holding each row's columns
  for (int i = 0; i < 4; ++i) {
    float v = lsum[i];
    v += __shfl_xor(v, 1); v += __shfl_xor(v, 2);
    v += __shfl_xor(v, 4); v += __shfl_xor(v, 8);
    lsum[i] = 1.0f / v;
  }
  for (int di = 0; di < 4; ++di)
    for (int i = 0; i < 4; ++i) {
      size_t ofs = (size_t)(b * 2048 + q0 + w * 16 + quad * 4 + i) * 1024 + h * 64 + di * 16 + lo;
      O[ofs] = f2bf(acco[di][i] * lsum[i]);
    }
}

// ---------- launch ----------
extern "C" void kernel_launch(void* const* d_in, const int* in_sizes, int n_in,
                              void* d_out, int out_size, void* d_ws, size_t ws_size,
                              hipStream_t stream) {
  const float* x   = (const float*)d_in[0];
  const float* R   = (const float*)d_in[1];
  const float* ent = (const float*)d_in[2];
  const float* Wq  = (const float*)d_in[3];
  const float* Wk  = (const float*)d_in[4];
  const float* Wv  = (const float*)d_in[5];
  const float* Wo  = (const float*)d_in[6];
  float* out = (float*)d_out;

  const size_t MLD = (size_t)4096 * 1024; // B*L x D
  const size_t DD  = (size_t)1024 * 1024;
  const size_t need = (MLD * 6 + DD * 9) * 2; // bytes
  if (ws_size < need) return; // workspace too small -> fail loudly via wrong output

  unsigned short* ws  = (unsigned short*)d_ws;
  unsigned short* xb  = ws;         // x bf16
  unsigned short* RT  = xb + MLD;   // R^T
  unsigned short* WqT = RT + DD;
  unsigned short* WkT = WqT + DD;
  unsigned short* WvT = WkT + DD;
  unsigned short* Wob = WvT + DD;   // Wo (straight)
  unsigned short* AqT = Wob + DD;   // (Wq^T R)^T
  unsigned short* AkT = AqT + DD;
  unsigned short* AvT = AkT + DD;
  unsigned short* Qb  = AvT + DD;   // Q = x Wq^T R
  unsigned short* Kb  = Qb + MLD;
  unsigned short* Vb  = Kb + MLD;
  unsigned short* Vtb = Vb + MLD;   // V^T (1024 x 4096)
  unsigned short* aO  = Vtb + MLD;  // attention output

  // converts / transposes
  cvt_f32_bf16<<<dim3((unsigned)(MLD / 4 / 256)), dim3(256), 0, stream>>>(x, xb, (int)(MLD / 4));
  cvt_f32_bf16<<<dim3((unsigned)(DD / 4 / 256)), dim3(256), 0, stream>>>(Wo, Wob, (int)(DD / 4));
  tr_f32_bf16<<<dim3(16, 16), dim3(256), 0, stream>>>(R,  RT,  1024, 1024);
  tr_f32_bf16<<<dim3(16, 16), dim3(256), 0, stream>>>(Wq, WqT, 1024, 1024);
  tr_f32_bf16<<<dim3(16, 16), dim3(256), 0, stream>>>(Wk, WkT, 1024, 1024);
  tr_f32_bf16<<<dim3(16, 16), dim3(256), 0, stream>>>(Wv, WvT, 1024, 1024);

  // A*T = NT(RT, W*T)  -> (W*^T R)^T, 1024^3, batched over z
  gemm_nt<true><<<dim3(8, 8, 3), dim3(256), 0, stream>>>(
      RT, WqT, WkT, WvT, (void*)AqT, (void*)AkT, (void*)AvT, 1024, 1024, 1024);
  // Q/K/V = NT(xb, A*T), 4096x1024x1024, batched over z
  gemm_nt<true><<<dim3(8, 32, 3), dim3(256), 0, stream>>>(
      xb, AqT, AkT, AvT, (void*)Qb, (void*)Kb, (void*)Vb, 4096, 1024, 1024);
  // V^T for the PV B-operand
  tr_bf16<<<dim3(16, 64), dim3(256), 0, stream>>>(Vb, Vtb, 4096, 1024);
  // attention
  flash_attn<<<dim3(32, 32), dim3(256), 0, stream>>>(Qb, Kb, Vtb, ent, aO);
  // out = NT(aO, Wob) -> fp32
  gemm_nt<false><<<dim3(8, 32, 1), dim3(256), 0, stream>>>(
      aO, Wob, Wob, Wob, (void*)out, (void*)out, (void*)out, 4096, 1024, 1024);
}

// Round 2
// 249.258 us; speedup vs baseline: 1.1735x; 1.1735x over previous
//
#include <hip/hip_runtime.h>
#include <cstdint>
#include <cstddef>

// ---------- types ----------
typedef __attribute__((ext_vector_type(8))) short  bf16x8;   // 8 bf16 = 4 VGPR (MFMA A/B frag)
typedef __attribute__((ext_vector_type(4))) float  f32x4;    // MFMA C/D frag
typedef __attribute__((ext_vector_type(4))) unsigned short u16x4;

#define LOG2E 1.44269504088896340736f

__device__ __forceinline__ unsigned short f2bf(float f) {
  unsigned int u = __builtin_bit_cast(unsigned int, f);
  u += 0x7fffu + ((u >> 16) & 1u);
  return (unsigned short)(u >> 16);
}
__device__ __forceinline__ float bf2f(unsigned short s) {
  unsigned int u = ((unsigned int)s) << 16;
  return __builtin_bit_cast(float, u);
}

// async global->LDS, 16B per lane (wave-uniform LDS base + lane*16)
__device__ __forceinline__ void gll16(const void* g, void* l) {
  __builtin_amdgcn_global_load_lds(
      (const __attribute__((address_space(1))) unsigned int*)g,
      (__attribute__((address_space(3))) unsigned int*)l, 16, 0, 0);
}

// ---------- fused converts: z=0 -> (s0,d0,n40), z=1 -> (s1,d1,n41) ----------
__global__ void cvt2(const float* __restrict__ s0, unsigned short* __restrict__ d0, int n40,
                     const float* __restrict__ s1, unsigned short* __restrict__ d1, int n41) {
  const float* s = blockIdx.y ? s1 : s0;
  unsigned short* d = blockIdx.y ? d1 : d0;
  int n4 = blockIdx.y ? n41 : n40;
  int i = blockIdx.x * blockDim.x + threadIdx.x;
  if (i < n4) {
    float4 v = ((const float4*)s)[i];
    u16x4 o;
    o[0] = f2bf(v.x); o[1] = f2bf(v.y); o[2] = f2bf(v.z); o[3] = f2bf(v.w);
    ((u16x4*)d)[i] = o;
  }
}

// ---------- batched transpose fp32(1024x1024) -> bf16 transposed, z selects ----------
__global__ void tr4(const float* __restrict__ s0, const float* __restrict__ s1,
                    const float* __restrict__ s2, const float* __restrict__ s3,
                    unsigned short* __restrict__ d0, unsigned short* __restrict__ d1,
                    unsigned short* __restrict__ d2, unsigned short* __restrict__ d3) {
  int z = blockIdx.z;
  const float* in = z == 0 ? s0 : (z == 1 ? s1 : (z == 2 ? s2 : s3));
  unsigned short* out = z == 0 ? d0 : (z == 1 ? d1 : (z == 2 ? d2 : d3));
  __shared__ unsigned short s[64][68];
  int t = threadIdx.x;
  int r0 = blockIdx.y * 64, c0 = blockIdx.x * 64;
  int tr = t >> 4, tc4 = (t & 15) * 4;
  for (int i = 0; i < 4; ++i) {
    int r = tr + i * 16;
    float4 v = *(const float4*)(in + (size_t)(r0 + r) * 1024 + c0 + tc4);
    s[r][tc4 + 0] = f2bf(v.x); s[r][tc4 + 1] = f2bf(v.y);
    s[r][tc4 + 2] = f2bf(v.z); s[r][tc4 + 3] = f2bf(v.w);
  }
  __syncthreads();
  for (int i = 0; i < 4; ++i) {
    int oc = tr + i * 16;
    u16x4 o;
    o[0] = s[tc4 + 0][oc]; o[1] = s[tc4 + 1][oc];
    o[2] = s[tc4 + 2][oc]; o[3] = s[tc4 + 3][oc];
    *(u16x4*)(out + (size_t)(c0 + oc) * 1024 + r0 + tc4) = o;
  }
}

// ---------- NT GEMM: C[M][N] = A[M][K]*B[N][K]^T, 128x128 tile, BK=64, XOR-swizzled LDS.
// z selects (B,C). If blockIdx.z==tz, C is written transposed (bf16, leading dim M).
template <bool BF16OUT>
__global__ __launch_bounds__(256) void gemm_nt(
    const unsigned short* __restrict__ A,
    const unsigned short* __restrict__ B0, const unsigned short* __restrict__ B1,
    const unsigned short* __restrict__ B2,
    void* __restrict__ C0, void* __restrict__ C1, void* __restrict__ C2,
    int M, int N, int K, int tz) {
  const unsigned short* B = blockIdx.z == 0 ? B0 : (blockIdx.z == 1 ? B1 : B2);
  void* Cv = blockIdx.z == 0 ? C0 : (blockIdx.z == 1 ? C1 : C2);

  __shared__ unsigned short As[128 * 64];
  __shared__ unsigned short Bs[128 * 64];

  int tid = threadIdx.x, w = tid >> 6, lane = tid & 63;
  int lo = lane & 15, quad = lane >> 4;
  int m0 = blockIdx.y * 128, n0 = blockIdx.x * 128;
  int wm = (w >> 1) * 64, wn = (w & 1) * 64;

  f32x4 z4 = {0.f, 0.f, 0.f, 0.f};
  f32x4 acc[4][4];
  for (int mi = 0; mi < 4; ++mi)
    for (int ni = 0; ni < 4; ++ni) acc[mi][ni] = z4;

  // staging: 16 chunks of 512 shorts; wave w covers chunks w*4..w*4+3 per matrix.
  // LDS slot (row r = c*8 + lane>>3, kchunk = lane&7) holds global kchunk (lane&7)^(r&7).
  int rloc = lane >> 3;
  int srcChunk = (lane & 7) ^ (rloc & 7);
  int cbase = w * 4;
  const unsigned short* Ag = A + (size_t)(m0 + cbase * 8 + rloc) * K + srcChunk * 8;
  const unsigned short* Bg = B + (size_t)(n0 + cbase * 8 + rloc) * K + srcChunk * 8;
  int ldsOfs = cbase * 512 + lane * 8;
  int cx0 = (quad ^ (lane & 7)) * 8;
  int cx1 = ((quad + 4) ^ (lane & 7)) * 8;

  for (int k0 = 0; k0 < K; k0 += 64) {
#pragma unroll
    for (int j = 0; j < 4; ++j) {
      gll16(Ag + (size_t)j * 8 * K + k0, As + ldsOfs + j * 512);
      gll16(Bg + (size_t)j * 8 * K + k0, Bs + ldsOfs + j * 512);
    }
    __syncthreads();
#pragma unroll
    for (int ks = 0; ks < 2; ++ks) {
      int cx = ks ? cx1 : cx0;
      bf16x8 af[4], bfr[4];
#pragma unroll
      for (int mi = 0; mi < 4; ++mi)
        af[mi] = *(const bf16x8*)(As + (wm + mi * 16 + lo) * 64 + cx);
#pragma unroll
      for (int ni = 0; ni < 4; ++ni)
        bfr[ni] = *(const bf16x8*)(Bs + (wn + ni * 16 + lo) * 64 + cx);
#pragma unroll
      for (int mi = 0; mi < 4; ++mi)
#pragma unroll
        for (int ni = 0; ni < 4; ++ni)
          acc[mi][ni] = __builtin_amdgcn_mfma_f32_16x16x32_bf16(af[mi], bfr[ni], acc[mi][ni], 0, 0, 0);
    }
    __syncthreads();
  }

  if ((int)blockIdx.z == tz) {
    // transposed bf16 epilogue: C^T[c][r], leading dim M
#pragma unroll
    for (int mi = 0; mi < 4; ++mi)
#pragma unroll
      for (int ni = 0; ni < 4; ++ni) {
        u16x4 o;
        for (int i = 0; i < 4; ++i) o[i] = f2bf(acc[mi][ni][i]);
        int c = n0 + wn + ni * 16 + lo;
        int rb = m0 + wm + mi * 16 + quad * 4;
        *(u16x4*)((unsigned short*)Cv + (size_t)c * M + rb) = o;
      }
  } else {
#pragma unroll
    for (int mi = 0; mi < 4; ++mi)
#pragma unroll
      for (int ni = 0; ni < 4; ++ni)
        for (int i = 0; i < 4; ++i) {
          int r = m0 + wm + mi * 16 + quad * 4 + i;
          int c = n0 + wn + ni * 16 + lo;
          if (BF16OUT)
            ((unsigned short*)Cv)[(size_t)r * N + c] = f2bf(acc[mi][ni][i]);
          else
            ((float*)Cv)[(size_t)r * N + c] = acc[mi][ni][i];
        }
  }
}

// ---------- flash attention, no-max online softmax, 32 q-rows/wave ----------
// Q,K: bf16 [4096][1024]; Vt: bf16 [1024][4096]; O: bf16 [4096][1024].
// Block = 128 threads (2 waves) x 64 q-rows; KV tiles of 64; XOR-swizzled LDS.
__global__ __launch_bounds__(128) void flash_attn(
    const unsigned short* __restrict__ Q, const unsigned short* __restrict__ Kg_,
    const unsigned short* __restrict__ Vt, const float* __restrict__ ent,
    unsigned short* __restrict__ O) {
  int tid = threadIdx.x, w = tid >> 6, lane = tid & 63;
  int lo = lane & 15, quad = lane >> 4;
  int b = blockIdx.y >> 4, h = blockIdx.y & 15;
  int q0 = blockIdx.x * 64;
  float scale = ent[h] * (0.125f * LOG2E);

  __shared__ unsigned short Ks[64 * 64];
  __shared__ unsigned short Vts[64 * 64];   // [d][l]
  __shared__ unsigned short Ps[2][32 * 64]; // per-wave P tile, swizzled

  // Q fragments straight from global, scale folded in. aq[t][ks]: rows w*32+t*16+lo.
  bf16x8 aq[2][2];
#pragma unroll
  for (int t = 0; t < 2; ++t)
#pragma unroll
    for (int ks = 0; ks < 2; ++ks) {
      uint4 v = *(const uint4*)(Q + (size_t)(b * 2048 + q0 + w * 32 + t * 16 + lo) * 1024 +
                                h * 64 + ks * 32 + quad * 8);
      unsigned int* pv = (unsigned int*)&v;
      uint4 o; unsigned int* po = (unsigned int*)&o;
#pragma unroll
      for (int j = 0; j < 4; ++j) {
        float f0 = bf2f((unsigned short)(pv[j] & 0xffffu)) * scale;
        float f1 = bf2f((unsigned short)(pv[j] >> 16)) * scale;
        po[j] = (unsigned int)f2bf(f0) | ((unsigned int)f2bf(f1) << 16);
      }
      aq[t][ks] = *(bf16x8*)&o;
    }

  f32x4 z4 = {0.f, 0.f, 0.f, 0.f};
  f32x4 acco[2][4];
#pragma unroll
  for (int t = 0; t < 2; ++t)
    for (int di = 0; di < 4; ++di) acco[t][di] = z4;
  float lsum[2][4] = {{0.f, 0.f, 0.f, 0.f}, {0.f, 0.f, 0.f, 0.f}};

  int rloc = lane >> 3;
  int srcChunk = (lane & 7) ^ (rloc & 7);
  int cb = w * 4;
  const unsigned short* Kp = Kg_ + (size_t)(b * 2048) * 1024 + h * 64;
  const unsigned short* Vp = Vt + (size_t)(h * 64) * 4096 + (size_t)b * 2048;
  int cx0 = (quad ^ (lane & 7)) * 8;
  int cx1 = ((quad + 4) ^ (lane & 7)) * 8;
  unsigned short* Pw = Ps[w];

  for (int kv0 = 0; kv0 < 2048; kv0 += 64) {
#pragma unroll
    for (int j = 0; j < 4; ++j) {
      int c = cb + j;
      int r = c * 8 + rloc;
      gll16(Kp + (size_t)(kv0 + r) * 1024 + srcChunk * 8, Ks + c * 512 + lane * 8);
      gll16(Vp + (size_t)r * 4096 + kv0 + srcChunk * 8, Vts + c * 512 + lane * 8);
    }
    __syncthreads();

    // S = Q.K^T : 32 q x 64 kv per wave
    f32x4 accs[2][4];
#pragma unroll
    for (int t = 0; t < 2; ++t)
      for (int ni = 0; ni < 4; ++ni) accs[t][ni] = z4;
#pragma unroll
    for (int ks = 0; ks < 2; ++ks) {
      int cx = ks ? cx1 : cx0;
#pragma unroll
      for (int ni = 0; ni < 4; ++ni) {
        bf16x8 bk = *(const bf16x8*)(Ks + (ni * 16 + lo) * 64 + cx);
        accs[0][ni] = __builtin_amdgcn_mfma_f32_16x16x32_bf16(aq[0][ks], bk, accs[0][ni], 0, 0, 0);
        accs[1][ni] = __builtin_amdgcn_mfma_f32_16x16x32_bf16(aq[1][ks], bk, accs[1][ni], 0, 0, 0);
      }
    }

    // P = 2^S, row sums, C-layout -> swizzled LDS
#pragma unroll
    for (int t = 0; t < 2; ++t)
#pragma unroll
      for (int ni = 0; ni < 4; ++ni)
#pragma unroll
        for (int i = 0; i < 4; ++i) {
          float p = exp2f(accs[t][ni][i]);
          lsum[t][i] += p;
          int row = t * 16 + quad * 4 + i;
          int cx2 = ((ni * 2 + (lo >> 3)) ^ ((quad * 4 + i) & 7)) * 8;
          Pw[row * 64 + cx2 + (lo & 7)] = f2bf(p);
        }

    // O += P.V (same-wave LDS RAW)
#pragma unroll
    for (int ks = 0; ks < 2; ++ks) {
      int cx = ks ? cx1 : cx0;
      bf16x8 ap0 = *(const bf16x8*)(Pw + (lo) * 64 + cx);
      bf16x8 ap1 = *(const bf16x8*)(Pw + (16 + lo) * 64 + cx);
#pragma unroll
      for (int di = 0; di < 4; ++di) {
        bf16x8 bv = *(const bf16x8*)(Vts + (di * 16 + lo) * 64 + cx);
        acco[0][di] = __builtin_amdgcn_mfma_f32_16x16x32_bf16(ap0, bv, acco[0][di], 0, 0, 0);
        acco[1][di] = __builtin_amdgcn_mfma_f32_16x16x32_bf16(ap1, bv, acco[1][di], 0, 0, 0);
      }
    }
    __syncthreads();
  }

  // normalize + store
#pragma unroll
  for (int t = 0; t < 2; ++t)
#pragma unroll
    for (int i = 0; i < 4; ++i) {
      float v = lsum[t][i];
      v += __shfl_xor(v, 1); v += __shfl_xor(v, 2);
      v += __shfl_xor(v, 4); v += __shfl_xor(v, 8);
      lsum[t][i] = 1.0f / v;
    }
#pragma unroll
  for (int t = 0; t < 2; ++t)
#pragma unroll
    for (int di = 0; di < 4; ++di)
      for (int i = 0; i < 4; ++i) {
        size_t ofs = (size_t)(b * 2048 + q0 + w * 32 + t * 16 + quad * 4 + i) * 1024 +
                     h * 64 + di * 16 + lo;
        O[ofs] = f2bf(acco[t][di][i] * lsum[t][i]);
      }
}

// ---------- launch ----------
extern "C" void kernel_launch(void* const* d_in, const int* in_sizes, int n_in,
                              void* d_out, int out_size, void* d_ws, size_t ws_size,
                              hipStream_t stream) {
  const float* x   = (const float*)d_in[0];
  const float* R   = (const float*)d_in[1];
  const float* ent = (const float*)d_in[2];
  const float* Wq  = (const float*)d_in[3];
  const float* Wk  = (const float*)d_in[4];
  const float* Wv  = (const float*)d_in[5];
  const float* Wo  = (const float*)d_in[6];
  float* out = (float*)d_out;

  const size_t MLD = (size_t)4096 * 1024;
  const size_t DD  = (size_t)1024 * 1024;

  unsigned short* ws  = (unsigned short*)d_ws;
  unsigned short* xb  = ws;         // x bf16              4M
  unsigned short* RT  = xb + MLD;   // R^T                 1M
  unsigned short* WqT = RT + DD;
  unsigned short* WkT = WqT + DD;
  unsigned short* WvT = WkT + DD;
  unsigned short* Wob = WvT + DD;   // Wo straight
  unsigned short* AqT = Wob + DD;   // (Wq^T R)^T
  unsigned short* AkT = AqT + DD;
  unsigned short* AvT = AkT + DD;
  unsigned short* Qb  = AvT + DD;   // 4M
  unsigned short* Kb  = Qb + MLD;   // 4M
  unsigned short* Vtb = Kb + MLD;   // V^T [1024][4096], 4M
  unsigned short* aO  = Vtb + MLD;  // attention out, 4M

  // converts (x, Wo) in one launch
  cvt2<<<dim3(4096, 2), dim3(256), 0, stream>>>(
      x, xb, (int)(MLD / 4), Wo, Wob, (int)(DD / 4));
  // 4 weight transposes in one launch
  tr4<<<dim3(16, 16, 4), dim3(256), 0, stream>>>(R, Wq, Wk, Wv, RT, WqT, WkT, WvT);

  // A*T = NT(RT, W*T) = (W*^T R)^T
  gemm_nt<true><<<dim3(8, 8, 3), dim3(256), 0, stream>>>(
      RT, WqT, WkT, WvT, (void*)AqT, (void*)AkT, (void*)AvT, 1024, 1024, 1024, -1);
  // Q/K = NT(xb, A*T); V written transposed straight into Vtb (z==2)
  gemm_nt<true><<<dim3(8, 32, 3), dim3(256), 0, stream>>>(
      xb, AqT, AkT, AvT, (void*)Qb, (void*)Kb, (void*)Vtb, 4096, 1024, 1024, 2);
  // attention
  flash_attn<<<dim3(32, 32), dim3(128), 0, stream>>>(Qb, Kb, Vtb, ent, aO);
  // out = NT(aO, Wob) -> fp32
  gemm_nt<false><<<dim3(8, 32, 1), dim3(256), 0, stream>>>(
      aO, Wob, Wob, Wob, (void*)out, (void*)out, (void*)out, 4096, 1024, 1024, -1);
}